// Round 18
// baseline (317.478 us; speedup 1.0000x reference)
//
#include <hip/hip_runtime.h>
#include <hip/hip_bf16.h>
#include <math.h>

#define DIMC  256
#define HEADS 8
#define DH    64
#define INNER 512
#define TOPK  512
#define LQ    16384
#define LKE   4096
#define NB    2
#define NBH   16
#define QSPLIT 8

typedef __attribute__((ext_vector_type(8))) short bf16x8;
typedef __attribute__((ext_vector_type(4))) float f32x4;
typedef __attribute__((ext_vector_type(16))) unsigned u32x16;

__device__ __forceinline__ unsigned short f2bf(float f) {
    unsigned u = __float_as_uint(f);
    u += 0x7FFFu + ((u >> 16) & 1u);
    return (unsigned short)(u >> 16);
}
__device__ __forceinline__ float bf2f(unsigned short b) {
    return __uint_as_float(((unsigned)b) << 16);
}
__device__ __forceinline__ f32x4 mfma16(bf16x8 a, bf16x8 b, f32x4 c) {
    return __builtin_amdgcn_mfma_f32_16x16x32_bf16(a, b, c, 0, 0, 0);
}
__device__ __forceinline__ unsigned f2q16(float v) {  // monotone map [-1,1] -> u16
    return (unsigned)((int)rintf(v * 32000.0f) + 32768) & 0xFFFFu;
}

// -------- channel-LN stats for BOTH tensors in one launch --------
__global__ void stats_all_kernel(const float* __restrict__ ctx, const float* __restrict__ qs,
                                 float* __restrict__ mu_c, float* __restrict__ rs_c,
                                 float* __restrict__ mu_q, float* __restrict__ rs_q) {
    int idx = blockIdx.x * 256 + threadIdx.x;
    const float* x; float* mu; float* rs; int L; int li;
    if (idx < NB * LKE) { x = ctx; mu = mu_c; rs = rs_c; L = LKE; li = idx; }
    else { li = idx - NB * LKE; if (li >= NB * LQ) return; x = qs; mu = mu_q; rs = rs_q; L = LQ; }
    int b = li / L, l = li - b * L;
    const float* p = x + (size_t)b * DIMC * L + l;
    float s = 0.f, sq = 0.f;
    for (int c = 0; c < DIMC; c++) {
        float v = p[(size_t)c * L];
        s += v; sq += v * v;
    }
    float m = s * (1.0f / DIMC);
    float var = fmaxf(sq * (1.0f / DIMC) - m * m, 0.f);
    mu[li] = m;
    rs[li] = rsqrtf(var + 1e-5f);
}

// ------- LN + transpose to [b][L][C], bf16 hi (and optional lo) planes -------
template<bool WRITELO>
__global__ __launch_bounds__(256) void ln_transpose_kernel(
    const float* __restrict__ x, const float* __restrict__ mu, const float* __restrict__ rs,
    const float* __restrict__ g, const float* __restrict__ beta, int L,
    unsigned short* __restrict__ xhi, unsigned short* __restrict__ xlo) {
    int lt = blockIdx.x, ct = blockIdx.y, b = blockIdx.z;
    int l0 = lt * 64, c0 = ct * 64;
    int t = threadIdx.x;
    __shared__ float T[64][65];
#pragma unroll
    for (int r = 0; r < 16; r++) {
        int f = r * 256 + t;
        int l = f & 63, c = f >> 6;
        int loc = b * L + l0 + l;
        float v = x[((size_t)b * DIMC + c0 + c) * L + l0 + l];
        T[c][l] = (v - mu[loc]) * rs[loc] * g[c0 + c] + beta[c0 + c];
    }
    __syncthreads();
#pragma unroll
    for (int r = 0; r < 16; r++) {
        int f = r * 256 + t;
        int c = f & 63, l = f >> 6;
        float v = T[c][l];
        unsigned short hi = f2bf(v);
        size_t di = ((size_t)b * L + l0 + l) * DIMC + c0 + c;
        xhi[di] = hi;
        if (WRITELO) xlo[di] = f2bf(v - bf2f(hi));
    }
}

// ------------- MFMA GEMM, 128x128 tile, fused epilogues -------------
// MODE 0: KV proj; MODE 1: Q proj
template<int MODE>
__global__ __launch_bounds__(256) void gemm_mfma_kernel(
    const float* __restrict__ wmat,
    const unsigned short* __restrict__ xhi, const unsigned short* __restrict__ xlo,
    void* __restrict__ dst0, void* __restrict__ dst1, void* __restrict__ dst2) {
    constexpr int K = 256;
    constexpr int N = (MODE == 0) ? LKE : LQ;
    constexpr bool MAYSPLIT = (MODE == 0);
    int n0 = blockIdx.x * 128;
    int by = blockIdx.y;
    int bb = blockIdx.z;
    int t = threadIdx.x, w = t >> 6, lane = t & 63;
    int wm = w >> 1, wn = w & 1;
    int lanelo = lane & 15, lanehi = lane >> 4;

    __shared__ __align__(16) char Wh[16384];
    __shared__ __align__(16) char Xh[16384];
    __shared__ __align__(16) char Wl[MAYSPLIT ? 16384 : 16];
    __shared__ __align__(16) char Xl[MAYSPLIT ? 16384 : 16];

    bool split = MAYSPLIT && (by < 4);

    const float* wsrc = wmat + (size_t)by * 128 * K;
    const unsigned short* xsh = xhi + ((size_t)bb * N + n0) * K;
    const unsigned short* xsl = xlo + ((size_t)bb * N + n0) * K;

    f32x4 acc[4][4];
#pragma unroll
    for (int mi = 0; mi < 4; mi++)
#pragma unroll
        for (int ni = 0; ni < 4; ni++) acc[mi][ni] = (f32x4){0.f, 0.f, 0.f, 0.f};

    for (int k0 = 0; k0 < K; k0 += 64) {
        if (k0) __syncthreads();
#pragma unroll
        for (int gg = 0; gg < 4; gg++) {
            int e = gg * 2048 + t * 8;
            int row = e >> 6, kc = e & 63;
            const float* wp = wsrc + (size_t)row * K + k0 + kc;
            bf16x8 hi, lo;
#pragma unroll
            for (int i = 0; i < 8; i++) {
                float v = wp[i];
                unsigned short h = f2bf(v);
                hi[i] = (short)h;
                if (MAYSPLIT) lo[i] = (short)f2bf(v - bf2f(h));
            }
            int off = (row * 128 + kc * 2) ^ ((row & 7) << 4);
            *(bf16x8*)(Wh + off) = hi;
            *(bf16x8*)(Xh + off) = *(const bf16x8*)(xsh + (size_t)row * K + k0 + kc);
            if (split) {
                *(bf16x8*)(Wl + off) = lo;
                *(bf16x8*)(Xl + off) = *(const bf16x8*)(xsl + (size_t)row * K + k0 + kc);
            }
        }
        __syncthreads();
#pragma unroll
        for (int kk = 0; kk < 2; kk++) {
            bf16x8 ah[4], bh_[4];
#pragma unroll
            for (int mi = 0; mi < 4; mi++) {
                int row = wm * 64 + mi * 16 + lanelo;
                int off = (row * 128 + kk * 64 + lanehi * 16) ^ ((row & 7) << 4);
                ah[mi] = *(const bf16x8*)(Wh + off);
            }
#pragma unroll
            for (int ni = 0; ni < 4; ni++) {
                int row = wn * 64 + ni * 16 + lanelo;
                int off = (row * 128 + kk * 64 + lanehi * 16) ^ ((row & 7) << 4);
                bh_[ni] = *(const bf16x8*)(Xh + off);
            }
#pragma unroll
            for (int mi = 0; mi < 4; mi++)
#pragma unroll
                for (int ni = 0; ni < 4; ni++)
                    acc[mi][ni] = mfma16(ah[mi], bh_[ni], acc[mi][ni]);
            if (split) {
                bf16x8 al[4], bl_[4];
#pragma unroll
                for (int mi = 0; mi < 4; mi++) {
                    int row = wm * 64 + mi * 16 + lanelo;
                    int off = (row * 128 + kk * 64 + lanehi * 16) ^ ((row & 7) << 4);
                    al[mi] = *(const bf16x8*)(Wl + off);
                }
#pragma unroll
                for (int ni = 0; ni < 4; ni++) {
                    int row = wn * 64 + ni * 16 + lanelo;
                    int off = (row * 128 + kk * 64 + lanehi * 16) ^ ((row & 7) << 4);
                    bl_[ni] = *(const bf16x8*)(Xl + off);
                }
#pragma unroll
                for (int mi = 0; mi < 4; mi++)
#pragma unroll
                    for (int ni = 0; ni < 4; ni++) {
                        acc[mi][ni] = mfma16(ah[mi], bl_[ni], acc[mi][ni]);
                        acc[mi][ni] = mfma16(al[mi], bh_[ni], acc[mi][ni]);
                    }
            }
        }
    }

    bool donorm = (MODE == 1) || (MODE == 0 && by < 4);
    float inv[4];
    if (donorm) {
#pragma unroll
        for (int ni = 0; ni < 4; ni++) {
            float s = 0.f;
#pragma unroll
            for (int mi = 0; mi < 4; mi++)
#pragma unroll
                for (int rg = 0; rg < 4; rg++) s += acc[mi][ni][rg] * acc[mi][ni][rg];
            s += __shfl_xor(s, 16);
            s += __shfl_xor(s, 32);
            inv[ni] = 1.0f / fmaxf(sqrtf(s), 1e-12f);
        }
    }
#pragma unroll
    for (int mi = 0; mi < 4; mi++) {
        int rowg = by * 128 + wm * 64 + mi * 16 + lanehi * 4;
#pragma unroll
        for (int ni = 0; ni < 4; ni++) {
            int l = n0 + wn * 64 + ni * 16 + lanelo;
            if (MODE == 0) {
                bool isk = rowg < 512;
                float sc = isk ? inv[ni] : 1.0f;
                int h = (rowg >> 6) & 7, d0 = rowg & 63;
                float4 v = make_float4(acc[mi][ni][0] * sc, acc[mi][ni][1] * sc,
                                       acc[mi][ni][2] * sc, acc[mi][ni][3] * sc);
                float* dp = isk ? (float*)dst0 : (float*)dst1;
                size_t base = ((size_t)(bb * HEADS + h) * LKE + l) * 64 + d0;
                *(float4*)&dp[base] = v;
                if (isk) {
                    uint2 pk;
                    pk.x = f2q16(v.x) | (f2q16(v.y) << 16);
                    pk.y = f2q16(v.z) | (f2q16(v.w) << 16);
                    *(uint2*)&((unsigned*)dst2)[(((size_t)(bb * HEADS + h) * LKE + l) * 64 + d0) / 2] = pk;
                }
            } else {
                int h = rowg >> 6, d0 = rowg & 63;
                ushort4 u;
                u.x = f2bf(acc[mi][ni][0] * inv[ni]);
                u.y = f2bf(acc[mi][ni][1] * inv[ni]);
                u.z = f2bf(acc[mi][ni][2] * inv[ni]);
                u.w = f2bf(acc[mi][ni][3] * inv[ni]);
                unsigned short* qp = (unsigned short*)dst0;
                *(ushort4*)&qp[((size_t)(bb * HEADS + h) * LQ + l) * 64 + d0] = u;
            }
        }
    }
}

// -------- fused output: GEMM(w_out, afT) + per-location LN + residual --------
__global__ __launch_bounds__(256) void gemm_out_fused_kernel(
    const float* __restrict__ wmat,
    const unsigned short* __restrict__ afT,
    const float* __restrict__ g, const float* __restrict__ beta,
    const float* __restrict__ gamma, const float* __restrict__ qs_in,
    float* __restrict__ out) {
    int l0 = blockIdx.x * 64;
    int b  = blockIdx.y;
    int t = threadIdx.x, w = t >> 6, lane = t & 63;
    int lanelo = lane & 15, lanehi = lane >> 4;

    __shared__ __align__(16) char Wh[32768];
    __shared__ __align__(16) char Xh[8192];
    __shared__ float sLds[4][64];
    __shared__ float sqLds[4][64];
    __shared__ float gs[256], bs[256];

    gs[t] = g[t];
    bs[t] = beta[t];

    const unsigned short* xs = afT + ((size_t)b * LQ + l0) * 512;

    f32x4 acc[4][4];
#pragma unroll
    for (int mi = 0; mi < 4; mi++)
#pragma unroll
        for (int ni = 0; ni < 4; ni++) acc[mi][ni] = (f32x4){0.f, 0.f, 0.f, 0.f};

    int row0s = t >> 3, c80 = t & 7;
    int row1s = 32 + (t >> 3);
    int offs0 = (row0s * 128 + c80 * 16) ^ ((row0s & 7) << 4);
    int offs1 = (row1s * 128 + c80 * 16) ^ ((row1s & 7) << 4);

    for (int k0 = 0; k0 < 512; k0 += 64) {
        if (k0) __syncthreads();
#pragma unroll
        for (int gg = 0; gg < 8; gg++) {
            int row = gg * 32 + (t >> 3);
            int kc = (t & 7) * 8;
            const float* wp = wmat + (size_t)row * 512 + k0 + kc;
            bf16x8 hi;
#pragma unroll
            for (int i = 0; i < 8; i++) hi[i] = (short)f2bf(wp[i]);
            int off = (row * 128 + kc * 2) ^ ((row & 7) << 4);
            *(bf16x8*)(Wh + off) = hi;
        }
        *(bf16x8*)(Xh + offs0) = *(const bf16x8*)(xs + (size_t)row0s * 512 + k0 + c80 * 8);
        *(bf16x8*)(Xh + offs1) = *(const bf16x8*)(xs + (size_t)row1s * 512 + k0 + c80 * 8);
        __syncthreads();
#pragma unroll
        for (int kk = 0; kk < 2; kk++) {
            bf16x8 ah[4], bh_[4];
#pragma unroll
            for (int mi = 0; mi < 4; mi++) {
                int row = w * 64 + mi * 16 + lanelo;
                int off = (row * 128 + kk * 64 + lanehi * 16) ^ ((row & 7) << 4);
                ah[mi] = *(const bf16x8*)(Wh + off);
            }
#pragma unroll
            for (int ni = 0; ni < 4; ni++) {
                int row = ni * 16 + lanelo;
                int off = (row * 128 + kk * 64 + lanehi * 16) ^ ((row & 7) << 4);
                bh_[ni] = *(const bf16x8*)(Xh + off);
            }
#pragma unroll
            for (int mi = 0; mi < 4; mi++)
#pragma unroll
                for (int ni = 0; ni < 4; ni++)
                    acc[mi][ni] = mfma16(ah[mi], bh_[ni], acc[mi][ni]);
        }
    }

#pragma unroll
    for (int ni = 0; ni < 4; ni++) {
        float s = 0.f, sq = 0.f;
#pragma unroll
        for (int mi = 0; mi < 4; mi++)
#pragma unroll
            for (int rg = 0; rg < 4; rg++) {
                float v = acc[mi][ni][rg];
                s += v; sq += v * v;
            }
        s += __shfl_xor(s, 16);  s += __shfl_xor(s, 32);
        sq += __shfl_xor(sq, 16); sq += __shfl_xor(sq, 32);
        if (lanehi == 0) {
            sLds[w][ni * 16 + lanelo] = s;
            sqLds[w][ni * 16 + lanelo] = sq;
        }
    }
    __syncthreads();
    float mu_[4], rs_[4];
#pragma unroll
    for (int ni = 0; ni < 4; ni++) {
        int l = ni * 16 + lanelo;
        float s  = (sLds[0][l] + sLds[1][l]) + (sLds[2][l] + sLds[3][l]);
        float sq = (sqLds[0][l] + sqLds[1][l]) + (sqLds[2][l] + sqLds[3][l]);
        float m = s * (1.0f / 256.0f);
        float var = fmaxf(sq * (1.0f / 256.0f) - m * m, 0.f);
        mu_[ni] = m;
        rs_[ni] = rsqrtf(var + 1e-5f);
    }
    float gm = gamma[0];
#pragma unroll
    for (int mi = 0; mi < 4; mi++) {
#pragma unroll
        for (int ni = 0; ni < 4; ni++) {
            int l = ni * 16 + lanelo;
#pragma unroll
            for (int rg = 0; rg < 4; rg++) {
                int ch = w * 64 + mi * 16 + lanehi * 4 + rg;
                float xn = (acc[mi][ni][rg] - mu_[ni]) * rs_[ni] * gs[ch] + bs[ch];
                size_t oi = ((size_t)(b * DIMC + ch)) * LQ + l0 + l;
                out[oi] = gm * xn + qs_in[oi];
            }
        }
    }
}

// ------- exact f32 sampled-query recompute: LN -> w_q proj -> l2norm -> u16 ----
__global__ __launch_bounds__(256) void qsample_kernel(
    const float* __restrict__ x, const float* __restrict__ mu, const float* __restrict__ rs,
    const float* __restrict__ g, const float* __restrict__ beta,
    const float* __restrict__ w, const int* __restrict__ ridx,
    unsigned* __restrict__ Qint) {
    int lt = blockIdx.x, bh = blockIdx.y;
    int b = bh >> 3, h = bh & 7;
    int t = threadIdx.x, tx = t & 15, ty = t >> 4;
    __shared__ float Ws[64][33];
    __shared__ float Xs[32][65];
    __shared__ float Cs[64][65];
    __shared__ float nf[64];
    __shared__ int lidx[64];
    if (t < 64) lidx[t] = ridx[bh * TOPK + lt * 64 + t];
    __syncthreads();
    float acc[4][4];
#pragma unroll
    for (int a = 0; a < 4; a++)
#pragma unroll
        for (int c2 = 0; c2 < 4; c2++) acc[a][c2] = 0.f;
    for (int kc = 0; kc < DIMC; kc += 32) {
#pragma unroll
        for (int r = 0; r < 8; r++) {
            int f = r * 256 + t;
            int oi = f >> 5, kj = f & 31;
            Ws[oi][kj] = w[(size_t)(h * 64 + oi) * DIMC + kc + kj];
        }
#pragma unroll
        for (int r = 0; r < 8; r++) {
            int f = r * 256 + t;
            int kj = f >> 6, lj = f & 63;
            int l = lidx[lj];
            int loc = b * LQ + l;
            float v = x[(size_t)b * DIMC * LQ + (size_t)(kc + kj) * LQ + l];
            Xs[kj][lj] = (v - mu[loc]) * rs[loc] * g[kc + kj] + beta[kc + kj];
        }
        __syncthreads();
#pragma unroll
        for (int kj = 0; kj < 32; kj++) {
            float wr[4], xr[4];
#pragma unroll
            for (int a = 0; a < 4; a++) wr[a] = Ws[ty * 4 + a][kj];
#pragma unroll
            for (int c2 = 0; c2 < 4; c2++) xr[c2] = Xs[kj][tx * 4 + c2];
#pragma unroll
            for (int a = 0; a < 4; a++)
#pragma unroll
                for (int c2 = 0; c2 < 4; c2++) acc[a][c2] += wr[a] * xr[c2];
        }
        __syncthreads();
    }
#pragma unroll
    for (int a = 0; a < 4; a++)
#pragma unroll
        for (int c2 = 0; c2 < 4; c2++) Cs[ty * 4 + a][tx * 4 + c2] = acc[a][c2];
    __syncthreads();
    if (t < 64) {
        float sq = 0.f;
        for (int o = 0; o < 64; o++) { float v = Cs[o][t]; sq += v * v; }
        nf[t] = 1.0f / fmaxf(sqrtf(sq), 1e-12f);
    }
    __syncthreads();
#pragma unroll
    for (int r = 0; r < 8; r++) {
        int f = r * 256 + t;
        int dp = f & 31, lj = f >> 5;
        float v0 = Cs[dp * 2][lj] * nf[lj];
        float v1 = Cs[dp * 2 + 1][lj] * nf[lj];
        Qint[((size_t)bh * TOPK + (size_t)lt * 64 + lj) * 32 + dp] =
            f2q16(v0) | (f2q16(v1) << 16);
    }
}

// -------- L1 cdist + min via packed v_sad_u16; K in VGPRs, Q double-buffered ---
// grid (LKE/256, NBH, QSPLIT): 64 q-rows per wave (more TLP for SMEM latency).
__global__ __launch_bounds__(256) __attribute__((amdgpu_waves_per_eu(4, 4)))
void cdist_sad_kernel(
    const unsigned* __restrict__ kint,
    const unsigned* __restrict__ Qint,
    unsigned* __restrict__ min_dq) {   // [QSPLIT][NBH][LKE]
    int bh = blockIdx.y;
    int key = blockIdx.x * 256 + threadIdx.x;
    int qz = blockIdx.z;
    const unsigned* kp = kint + ((size_t)bh * LKE + key) * 32;
    unsigned k[32];
#pragma unroll
    for (int d8 = 0; d8 < 8; d8++) {
        uint4 v = *(const uint4*)(kp + d8 * 4);
        k[d8 * 4 + 0] = v.x; k[d8 * 4 + 1] = v.y;
        k[d8 * 4 + 2] = v.z; k[d8 * 4 + 3] = v.w;
    }
#pragma unroll
    for (int d = 0; d < 32; d++) asm volatile("" : "+v"(k[d]));

    unsigned long long qaddr = (unsigned long long)(const void*)
        (Qint + ((size_t)bh * TOPK + (size_t)qz * (TOPK / QSPLIT)) * 32);
    u32x16 qa0, qa1, qb0, qb1;
    asm volatile(
        "s_load_dwordx16 %0, %2, 0x00\n\t"
        "s_load_dwordx16 %1, %2, 0x40"
        : "=s"(qa0), "=s"(qa1) : "s"(qaddr));
    unsigned best = 0xFFFFFFFFu;

#define S1(ACC, KK, QQ) asm("v_sad_u16 %0, %1, %2, %0" : "+v"(ACC) : "v"(KK), "s"(QQ));
#define S16(QV, KB) \
    S1(a0, k[KB + 0], QV[0])  S1(a1, k[KB + 1], QV[1]) \
    S1(a2, k[KB + 2], QV[2])  S1(a3, k[KB + 3], QV[3]) \
    S1(a0, k[KB + 4], QV[4])  S1(a1, k[KB + 5], QV[5]) \
    S1(a2, k[KB + 6], QV[6])  S1(a3, k[KB + 7], QV[7]) \
    S1(a0, k[KB + 8], QV[8])  S1(a1, k[KB + 9], QV[9]) \
    S1(a2, k[KB + 10], QV[10]) S1(a3, k[KB + 11], QV[11]) \
    S1(a0, k[KB + 12], QV[12]) S1(a1, k[KB + 13], QV[13]) \
    S1(a2, k[KB + 14], QV[14]) S1(a3, k[KB + 15], QV[15])

    for (int qi = 0; qi < TOPK / QSPLIT; qi += 2) {
        asm volatile(
            "s_load_dwordx16 %0, %2, 0x80\n\t"
            "s_load_dwordx16 %1, %2, 0xc0"
            : "=s"(qb0), "=s"(qb1) : "s"(qaddr));
        asm volatile("s_waitcnt lgkmcnt(2)" : "+s"(qa0), "+s"(qa1));
        {
            unsigned a0 = 0, a1 = 0, a2 = 0, a3 = 0;
            S16(qa0, 0) S16(qa1, 16)
            best = min(best, (a0 + a1) + (a2 + a3));
        }
        qaddr += 256;
        asm volatile(
            "s_load_dwordx16 %0, %2, 0x00\n\t"
            "s_load_dwordx16 %1, %2, 0x40"
            : "=s"(qa0), "=s"(qa1) : "s"(qaddr));
        asm volatile("s_waitcnt lgkmcnt(2)" : "+s"(qb0), "+s"(qb1));
        {
            unsigned a0 = 0, a1 = 0, a2 = 0, a3 = 0;
            S16(qb0, 0) S16(qb1, 16)
            best = min(best, (a0 + a1) + (a2 + a3));
        }
    }
#undef S16
#undef S1
    min_dq[((size_t)qz * NBH + bh) * LKE + key] = best;
}

// ------- radix-select 512 smallest per row; parallel bucket scan --------------
__global__ void select_topk_kernel(const unsigned* __restrict__ min_dq, int* __restrict__ isel) {
    int bh = blockIdx.x;
    int t = threadIdx.x;  // 256
    __shared__ unsigned su[LKE];
    __shared__ int hist[256];
    __shared__ int scan[256];
    __shared__ int sb[2];
    for (int i = t; i < LKE; i += 256) {
        unsigned m0 = min_dq[(size_t)bh * LKE + i];
#pragma unroll
        for (int z = 1; z < QSPLIT; z++)
            m0 = min(m0, min_dq[(size_t)(z * NBH + bh) * LKE + i]);
        su[i] = m0;
    }
    unsigned prefix = 0, mask = 0;
    int need = TOPK;
    for (int shift = 24; shift >= 0; shift -= 8) {
        hist[t] = 0;
        __syncthreads();
        for (int i = t; i < LKE; i += 256) {
            unsigned u = su[i];
            if ((u & mask) == prefix) atomicAdd(&hist[(u >> shift) & 255], 1);
        }
        __syncthreads();
        scan[t] = hist[t];
        __syncthreads();
#pragma unroll
        for (int d = 1; d < 256; d <<= 1) {
            int v = (t >= d) ? scan[t - d] : 0;
            __syncthreads();
            scan[t] += v;
            __syncthreads();
        }
        int excl = (t == 0) ? 0 : scan[t - 1];
        if (scan[t] >= need && excl < need) {
            sb[0] = t;
            sb[1] = need - excl;
        }
        __syncthreads();
        prefix |= ((unsigned)sb[0]) << shift;
        mask |= (255u << shift);
        need = sb[1];
        __syncthreads();
    }
    if (t < 64) {
        int pos = 0, eqseen = 0;
        unsigned long long lanem1 = (t == 0) ? 0ull : ((1ull << t) - 1ull);
        for (int i0 = 0; i0 < LKE; i0 += 64) {
            unsigned u = su[i0 + t];
            bool lt = (u < prefix);
            bool eq = (u == prefix);
            unsigned long long be = __ballot(eq);
            int eqbefore = __popcll(be & lanem1);
            bool take = lt || (eq && (eqseen + eqbefore) < need);
            unsigned long long bt = __ballot(take);
            if (take) isel[bh * TOPK + pos + __popcll(bt & lanem1)] = i0 + t;
            pos += __popcll(bt);
            eqseen += __popcll(be);
        }
    }
}

// -------- gather selected K (straight) + V (transposed), one launch -----------
__global__ __launch_bounds__(256) void gather_kv_kernel(
    const float* __restrict__ kf, const float* __restrict__ vf,
    const int* __restrict__ isel,
    unsigned short* __restrict__ kselh, unsigned short* __restrict__ vTh) {
    int bh = blockIdx.y, kc = blockIdx.x * 64;
    int t = threadIdx.x;
    __shared__ float T[64][65];
    __shared__ int rows[64];
    if (t < 64) rows[t] = isel[bh * TOPK + kc + t];
    __syncthreads();
#pragma unroll
    for (int r = 0; r < 16; r++) {
        int f = r * 256 + t;
        int key = f >> 6, d = f & 63;
        kselh[((size_t)bh * TOPK + kc + key) * 64 + d] =
            f2bf(kf[((size_t)bh * LKE + rows[key]) * 64 + d]);
    }
#pragma unroll
    for (int r = 0; r < 4; r++) {
        int c = r * 256 + t;
        int row = c >> 4, c4 = c & 15;
        float4 v = *(const float4*)(vf + ((size_t)bh * LKE + rows[row]) * 64 + c4 * 4);
        T[row][c4 * 4 + 0] = v.x; T[row][c4 * 4 + 1] = v.y;
        T[row][c4 * 4 + 2] = v.z; T[row][c4 * 4 + 3] = v.w;
    }
    __syncthreads();
#pragma unroll
    for (int r = 0; r < 16; r++) {
        int f = r * 256 + t;
        int d = f >> 6, key = f & 63;
        vTh[(size_t)bh * 64 * TOPK + (size_t)d * TOPK + kc + key] = f2bf(T[key][d]);
    }
}

// ---------------- MFMA flash attention, 128 q-rows/block (R15 + setprio) ------
__global__ __launch_bounds__(256) void attn_mfma_kernel(
    const unsigned short* __restrict__ qh,
    const unsigned short* __restrict__ kselh,
    const unsigned short* __restrict__ vTh,
    unsigned short* __restrict__ afT) {
    int bh = blockIdx.y, rt = blockIdx.x;
    int bq = bh >> 3, h = bh & 7;
    int t = threadIdx.x, w = t >> 6, lane = t & 63;
    __shared__ unsigned short Ks[2][64 * 64];
    __shared__ unsigned short Vts[2][64 * 64];
    __shared__ unsigned short Ps[4][2][16 * 64];

    const unsigned short* qb = qh + ((size_t)bh * LQ + (size_t)rt * 128) * 64;
    const unsigned short* kb = kselh + (size_t)bh * TOPK * 64;
    const unsigned short* vb = vTh + (size_t)bh * 64 * TOPK;

    int lanelo = lane & 15, lanehi = lane >> 4;

    int row0s = t >> 3, c80 = t & 7;
    int row1s = 32 + (t >> 3), c81 = t & 7;
    int offs0 = (row0s * 128 + c80 * 16) ^ ((row0s & 7) << 4);
    int offs1 = (row1s * 128 + c81 * 16) ^ ((row1s & 7) << 4);

    bf16x8 qfrag[2][2];
#pragma unroll
    for (int s = 0; s < 2; s++)
#pragma unroll
        for (int kk = 0; kk < 2; kk++) {
            int row = s * 64 + w * 16 + lanelo;
            qfrag[s][kk] = *(const bf16x8*)(qb + (size_t)row * 64 + kk * 32 + lanehi * 8);
        }

    {
        *(bf16x8*)((char*)Ks[0] + offs0) = *(const bf16x8*)(kb + row0s * 64 + c80 * 8);
        *(bf16x8*)((char*)Ks[0] + offs1) = *(const bf16x8*)(kb + row1s * 64 + c81 * 8);
        *(bf16x8*)((char*)Vts[0] + offs0) = *(const bf16x8*)(vb + row0s * TOPK + c80 * 8);
        *(bf16x8*)((char*)Vts[0] + offs1) = *(const bf16x8*)(vb + row1s * TOPK + c81 * 8);
    }
    __syncthreads();

    f32x4 o[2][4];
#pragma unroll
    for (int s = 0; s < 2; s++)
#pragma unroll
        for (int m = 0; m < 4; m++) o[s][m] = (f32x4){0.f, 0.f, 0.f, 0.f};
    float part[2][4] = {{0.f, 0.f, 0.f, 0.f}, {0.f, 0.f, 0.f, 0.f}};
    int cur = 0;

    for (int ch = 0; ch < 8; ch++) {
        bf16x8 knx0, knx1, vnx0, vnx1;
        if (ch < 7) {
            int kc0 = (ch + 1) * 64;
            knx0 = *(const bf16x8*)(kb + (kc0 + row0s) * 64 + c80 * 8);
            knx1 = *(const bf16x8*)(kb + (kc0 + row1s) * 64 + c81 * 8);
            vnx0 = *(const bf16x8*)(vb + row0s * TOPK + kc0 + c80 * 8);
            vnx1 = *(const bf16x8*)(vb + row1s * TOPK + kc0 + c81 * 8);
        }
        bf16x8 kfr[4][2];
#pragma unroll
        for (int n = 0; n < 4; n++)
#pragma unroll
            for (int kk = 0; kk < 2; kk++) {
                int row = n * 16 + lanelo;
                kfr[n][kk] = *(const bf16x8*)((char*)Ks[cur] +
                    ((row * 128 + kk * 64 + lanehi * 16) ^ ((row & 7) << 4)));
            }
#pragma unroll
        for (int s = 0; s < 2; s++) {
            f32x4 sv[4];
            __builtin_amdgcn_s_setprio(1);
#pragma unroll
            for (int n = 0; n < 4; n++) {
                sv[n] = (f32x4){0.f, 0.f, 0.f, 0.f};
#pragma unroll
                for (int kk = 0; kk < 2; kk++)
                    sv[n] = mfma16(qfrag[s][kk], kfr[n][kk], sv[n]);
            }
            __builtin_amdgcn_s_setprio(0);
            unsigned short* pw = Ps[w][s];
#pragma unroll
            for (int n = 0; n < 4; n++) {
#pragma unroll
                for (int rg = 0; rg < 4; rg++) {
                    float p = __expf(sv[n][rg]);
                    unsigned short ph = (unsigned short)(__float_as_uint(p) >> 16);
                    part[s][rg] += bf2f(ph);
                    int row = lanehi * 4 + rg, col = n * 16 + lanelo;
                    *(unsigned short*)((char*)pw +
                        ((row * 128 + col * 2) ^ ((row & 7) << 4))) = ph;
                }
            }
        }
        bf16x8 vfr[4][2];
#pragma unroll
        for (int m = 0; m < 4; m++)
#pragma unroll
            for (int kk = 0; kk < 2; kk++) {
                int row = m * 16 + lanelo;
                vfr[m][kk] = *(const bf16x8*)((char*)Vts[cur] +
                    ((row * 128 + kk * 64 + lanehi * 16) ^ ((row & 7) << 4)));
            }
#pragma unroll
        for (int s = 0; s < 2; s++) {
            bf16x8 pfrag[2];
#pragma unroll
            for (int kk = 0; kk < 2; kk++) {
                int row = lanelo;
                pfrag[kk] = *(const bf16x8*)((char*)Ps[w][s] +
                    ((row * 128 + kk * 64 + lanehi * 16) ^ ((row & 7) << 4)));
            }
            __builtin_amdgcn_s_setprio(1);
#pragma unroll
            for (int m = 0; m < 4; m++)
#pragma unroll
                for (int kk = 0; kk < 2; kk++)
                    o[s][m] = mfma16(pfrag[kk], vfr[m][kk], o[s][m]);
            __builtin_amdgcn_s_setprio(0);
        }
        if (ch < 7) {
            *(bf16x8*)((char*)Ks[cur ^ 1] + offs0) = knx0;
            *(bf16x8*)((char*)Ks[cur ^ 1] + offs1) = knx1;
            *(bf16x8*)((char*)Vts[cur ^ 1] + offs0) = vnx0;
            *(bf16x8*)((char*)Vts[cur ^ 1] + offs1) = vnx1;
        }
        __syncthreads();
        cur ^= 1;
    }
#pragma unroll
    for (int s = 0; s < 2; s++) {
#pragma unroll
        for (int rg = 0; rg < 4; rg++) {
            float v = part[s][rg];
            v += __shfl_xor(v, 1); v += __shfl_xor(v, 2);
            v += __shfl_xor(v, 4); v += __shfl_xor(v, 8);
            float invs = 1.0f / v;
            int l = rt * 128 + s * 64 + w * 16 + lanehi * 4 + rg;
            size_t base = ((size_t)bq * LQ + l) * 512 + h * 64 + lanelo;
#pragma unroll
            for (int m = 0; m < 4; m++)
                afT[base + m * 16] = f2bf(o[s][m][rg] * invs);
        }
    }
}

extern "C" void kernel_launch(void* const* d_in, const int* in_sizes, int n_in,
                              void* d_out, int out_size, void* d_ws, size_t ws_size,
                              hipStream_t stream) {
    const float* qs_in = (const float*)d_in[0];
    const float* ctx   = (const float*)d_in[1];
    const int*   ridx  = (const int*)d_in[2];
    const float* g_ctx = (const float*)d_in[3];
    const float* b_ctx = (const float*)d_in[4];
    const float* g_qs  = (const float*)d_in[5];
    const float* b_qs  = (const float*)d_in[6];
    const float* w_kv  = (const float*)d_in[7];
    const float* w_q   = (const float*)d_in[8];
    const float* w_out = (const float*)d_in[9];
    const float* g_out = (const float*)d_in[10];
    const float* b_out = (const float*)d_in[11];
    const float* gamma = (const float*)d_in[12];
    float* out = (float*)d_out;

    char* ws = (char*)d_ws;
    size_t off = 0;
    auto alloc = [&](size_t bytes) { char* p = ws + off; off += (bytes + 255) & ~(size_t)255; return p; };

    float*          kf    = (float*)alloc((size_t)NBH * LKE * 64 * 4);
    float*          vf    = (float*)alloc((size_t)NBH * LKE * 64 * 4);
    unsigned*       kint  = (unsigned*)alloc((size_t)NBH * LKE * 32 * 4);
    unsigned short* qh    = (unsigned short*)alloc((size_t)NBH * LQ * 64 * 2);
    char*           uni   = alloc((size_t)NB * LQ * INNER * 2);
    unsigned short* ctxT_hi = (unsigned short*)(uni);
    unsigned short* ctxT_lo = (unsigned short*)(uni + (size_t)NB * LKE * DIMC * 2);
    unsigned short* qsT_hi  = (unsigned short*)(uni + (size_t)2 * NB * LKE * DIMC * 2);
    unsigned short* afT     = (unsigned short*)(uni);

    unsigned*       Qint  = (unsigned*)alloc((size_t)NBH * TOPK * 32 * 4);
    unsigned short* kselh = (unsigned short*)alloc((size_t)NBH * TOPK * 64 * 2);
    unsigned short* vTh   = (unsigned short*)alloc((size_t)NBH * 64 * TOPK * 2);
    unsigned*       min_dq= (unsigned*)alloc((size_t)QSPLIT * NBH * LKE * 4);
    float*          mu_c  = (float*)alloc(NB * LKE * 4);
    float*          rs_c  = (float*)alloc(NB * LKE * 4);
    float*          mu_q  = (float*)alloc(NB * LQ * 4);
    float*          rs_q  = (float*)alloc(NB * LQ * 4);
    int*            isel  = (int*)alloc(NBH * TOPK * 4);

    stats_all_kernel<<<(NB * (LKE + LQ)) / 256, 256, 0, stream>>>(
        ctx, qs_in, mu_c, rs_c, mu_q, rs_q);
    ln_transpose_kernel<true><<<dim3(LKE / 64, DIMC / 64, NB), 256, 0, stream>>>(
        ctx, mu_c, rs_c, g_ctx, b_ctx, LKE, ctxT_hi, ctxT_lo);
    ln_transpose_kernel<false><<<dim3(LQ / 64, DIMC / 64, NB), 256, 0, stream>>>(
        qs_in, mu_q, rs_q, g_qs, b_qs, LQ, qsT_hi, nullptr);
    gemm_mfma_kernel<0><<<dim3(LKE / 128, 8, NB), 256, 0, stream>>>(
        w_kv, ctxT_hi, ctxT_lo, kf, vf, kint);
    gemm_mfma_kernel<1><<<dim3(LQ / 128, 4, NB), 256, 0, stream>>>(
        w_q, qsT_hi, qsT_hi, qh, nullptr, nullptr);
    qsample_kernel<<<dim3(TOPK / 64, NBH), 256, 0, stream>>>(
        qs_in, mu_q, rs_q, g_qs, b_qs, w_q, ridx, Qint);
    cdist_sad_kernel<<<dim3(LKE / 256, NBH, QSPLIT), 256, 0, stream>>>(kint, Qint, min_dq);
    select_topk_kernel<<<NBH, 256, 0, stream>>>(min_dq, isel);
    gather_kv_kernel<<<dim3(TOPK / 64, NBH), 256, 0, stream>>>(kf, vf, isel, kselh, vTh);
    attn_mfma_kernel<<<dim3(LQ / 128, NBH), 256, 0, stream>>>(qh, kselh, vTh, afT);
    gemm_out_fused_kernel<<<dim3(LQ / 64, NB), 256, 0, stream>>>(
        w_out, afT, g_out, b_out, gamma, qs_in, out);
}

// Round 19
// 298.888 us; speedup vs baseline: 1.0622x; 1.0622x over previous
//
#include <hip/hip_runtime.h>
#include <hip/hip_bf16.h>
#include <math.h>

#define DIMC  256
#define HEADS 8
#define DH    64
#define INNER 512
#define TOPK  512
#define LQ    16384
#define LKE   4096
#define NB    2
#define NBH   16

typedef __attribute__((ext_vector_type(8))) short bf16x8;
typedef __attribute__((ext_vector_type(4))) float f32x4;
typedef __attribute__((ext_vector_type(16))) unsigned u32x16;

__device__ __forceinline__ unsigned short f2bf(float f) {
    unsigned u = __float_as_uint(f);
    u += 0x7FFFu + ((u >> 16) & 1u);
    return (unsigned short)(u >> 16);
}
__device__ __forceinline__ float bf2f(unsigned short b) {
    return __uint_as_float(((unsigned)b) << 16);
}
__device__ __forceinline__ f32x4 mfma16(bf16x8 a, bf16x8 b, f32x4 c) {
    return __builtin_amdgcn_mfma_f32_16x16x32_bf16(a, b, c, 0, 0, 0);
}
__device__ __forceinline__ unsigned f2q16(float v) {  // monotone map [-1,1] -> u16
    return (unsigned)((int)rintf(v * 32000.0f) + 32768) & 0xFFFFu;
}

// -------- channel-LN stats for BOTH tensors in one launch --------
__global__ void stats_all_kernel(const float* __restrict__ ctx, const float* __restrict__ qs,
                                 float* __restrict__ mu_c, float* __restrict__ rs_c,
                                 float* __restrict__ mu_q, float* __restrict__ rs_q) {
    int idx = blockIdx.x * 256 + threadIdx.x;
    const float* x; float* mu; float* rs; int L; int li;
    if (idx < NB * LKE) { x = ctx; mu = mu_c; rs = rs_c; L = LKE; li = idx; }
    else { li = idx - NB * LKE; if (li >= NB * LQ) return; x = qs; mu = mu_q; rs = rs_q; L = LQ; }
    int b = li / L, l = li - b * L;
    const float* p = x + (size_t)b * DIMC * L + l;
    float s = 0.f, sq = 0.f;
    for (int c = 0; c < DIMC; c++) {
        float v = p[(size_t)c * L];
        s += v; sq += v * v;
    }
    float m = s * (1.0f / DIMC);
    float var = fmaxf(sq * (1.0f / DIMC) - m * m, 0.f);
    mu[li] = m;
    rs[li] = rsqrtf(var + 1e-5f);
}

// ------- LN + transpose to [b][L][C], bf16 hi (and optional lo) planes -------
template<bool WRITELO>
__global__ __launch_bounds__(256) void ln_transpose_kernel(
    const float* __restrict__ x, const float* __restrict__ mu, const float* __restrict__ rs,
    const float* __restrict__ g, const float* __restrict__ beta, int L,
    unsigned short* __restrict__ xhi, unsigned short* __restrict__ xlo) {
    int lt = blockIdx.x, ct = blockIdx.y, b = blockIdx.z;
    int l0 = lt * 64, c0 = ct * 64;
    int t = threadIdx.x;
    __shared__ float T[64][65];
#pragma unroll
    for (int r = 0; r < 16; r++) {
        int f = r * 256 + t;
        int l = f & 63, c = f >> 6;
        int loc = b * L + l0 + l;
        float v = x[((size_t)b * DIMC + c0 + c) * L + l0 + l];
        T[c][l] = (v - mu[loc]) * rs[loc] * g[c0 + c] + beta[c0 + c];
    }
    __syncthreads();
#pragma unroll
    for (int r = 0; r < 16; r++) {
        int f = r * 256 + t;
        int c = f & 63, l = f >> 6;
        float v = T[c][l];
        unsigned short hi = f2bf(v);
        size_t di = ((size_t)b * L + l0 + l) * DIMC + c0 + c;
        xhi[di] = hi;
        if (WRITELO) xlo[di] = f2bf(v - bf2f(hi));
    }
}

// ------------- MFMA GEMM, 128x128 tile, fused epilogues -------------
// MODE 0: KV proj; MODE 1: Q proj
template<int MODE>
__global__ __launch_bounds__(256) void gemm_mfma_kernel(
    const float* __restrict__ wmat,
    const unsigned short* __restrict__ xhi, const unsigned short* __restrict__ xlo,
    void* __restrict__ dst0, void* __restrict__ dst1, void* __restrict__ dst2) {
    constexpr int K = 256;
    constexpr int N = (MODE == 0) ? LKE : LQ;
    constexpr bool MAYSPLIT = (MODE == 0);
    int n0 = blockIdx.x * 128;
    int by = blockIdx.y;
    int bb = blockIdx.z;
    int t = threadIdx.x, w = t >> 6, lane = t & 63;
    int wm = w >> 1, wn = w & 1;
    int lanelo = lane & 15, lanehi = lane >> 4;

    __shared__ __align__(16) char Wh[16384];
    __shared__ __align__(16) char Xh[16384];
    __shared__ __align__(16) char Wl[MAYSPLIT ? 16384 : 16];
    __shared__ __align__(16) char Xl[MAYSPLIT ? 16384 : 16];

    bool split = MAYSPLIT && (by < 4);

    const float* wsrc = wmat + (size_t)by * 128 * K;
    const unsigned short* xsh = xhi + ((size_t)bb * N + n0) * K;
    const unsigned short* xsl = xlo + ((size_t)bb * N + n0) * K;

    f32x4 acc[4][4];
#pragma unroll
    for (int mi = 0; mi < 4; mi++)
#pragma unroll
        for (int ni = 0; ni < 4; ni++) acc[mi][ni] = (f32x4){0.f, 0.f, 0.f, 0.f};

    for (int k0 = 0; k0 < K; k0 += 64) {
        if (k0) __syncthreads();
#pragma unroll
        for (int gg = 0; gg < 4; gg++) {
            int e = gg * 2048 + t * 8;
            int row = e >> 6, kc = e & 63;
            const float* wp = wsrc + (size_t)row * K + k0 + kc;
            bf16x8 hi, lo;
#pragma unroll
            for (int i = 0; i < 8; i++) {
                float v = wp[i];
                unsigned short h = f2bf(v);
                hi[i] = (short)h;
                if (MAYSPLIT) lo[i] = (short)f2bf(v - bf2f(h));
            }
            int off = (row * 128 + kc * 2) ^ ((row & 7) << 4);
            *(bf16x8*)(Wh + off) = hi;
            *(bf16x8*)(Xh + off) = *(const bf16x8*)(xsh + (size_t)row * K + k0 + kc);
            if (split) {
                *(bf16x8*)(Wl + off) = lo;
                *(bf16x8*)(Xl + off) = *(const bf16x8*)(xsl + (size_t)row * K + k0 + kc);
            }
        }
        __syncthreads();
#pragma unroll
        for (int kk = 0; kk < 2; kk++) {
            bf16x8 ah[4], bh_[4];
#pragma unroll
            for (int mi = 0; mi < 4; mi++) {
                int row = wm * 64 + mi * 16 + lanelo;
                int off = (row * 128 + kk * 64 + lanehi * 16) ^ ((row & 7) << 4);
                ah[mi] = *(const bf16x8*)(Wh + off);
            }
#pragma unroll
            for (int ni = 0; ni < 4; ni++) {
                int row = wn * 64 + ni * 16 + lanelo;
                int off = (row * 128 + kk * 64 + lanehi * 16) ^ ((row & 7) << 4);
                bh_[ni] = *(const bf16x8*)(Xh + off);
            }
#pragma unroll
            for (int mi = 0; mi < 4; mi++)
#pragma unroll
                for (int ni = 0; ni < 4; ni++)
                    acc[mi][ni] = mfma16(ah[mi], bh_[ni], acc[mi][ni]);
            if (split) {
                bf16x8 al[4], bl_[4];
#pragma unroll
                for (int mi = 0; mi < 4; mi++) {
                    int row = wm * 64 + mi * 16 + lanelo;
                    int off = (row * 128 + kk * 64 + lanehi * 16) ^ ((row & 7) << 4);
                    al[mi] = *(const bf16x8*)(Wl + off);
                }
#pragma unroll
                for (int ni = 0; ni < 4; ni++) {
                    int row = wn * 64 + ni * 16 + lanelo;
                    int off = (row * 128 + kk * 64 + lanehi * 16) ^ ((row & 7) << 4);
                    bl_[ni] = *(const bf16x8*)(Xl + off);
                }
#pragma unroll
                for (int mi = 0; mi < 4; mi++)
#pragma unroll
                    for (int ni = 0; ni < 4; ni++) {
                        acc[mi][ni] = mfma16(ah[mi], bl_[ni], acc[mi][ni]);
                        acc[mi][ni] = mfma16(al[mi], bh_[ni], acc[mi][ni]);
                    }
            }
        }
    }

    bool donorm = (MODE == 1) || (MODE == 0 && by < 4);
    float inv[4];
    if (donorm) {
#pragma unroll
        for (int ni = 0; ni < 4; ni++) {
            float s = 0.f;
#pragma unroll
            for (int mi = 0; mi < 4; mi++)
#pragma unroll
                for (int rg = 0; rg < 4; rg++) s += acc[mi][ni][rg] * acc[mi][ni][rg];
            s += __shfl_xor(s, 16);
            s += __shfl_xor(s, 32);
            inv[ni] = 1.0f / fmaxf(sqrtf(s), 1e-12f);
        }
    }
#pragma unroll
    for (int mi = 0; mi < 4; mi++) {
        int rowg = by * 128 + wm * 64 + mi * 16 + lanehi * 4;
#pragma unroll
        for (int ni = 0; ni < 4; ni++) {
            int l = n0 + wn * 64 + ni * 16 + lanelo;
            if (MODE == 0) {
                bool isk = rowg < 512;
                float sc = isk ? inv[ni] : 1.0f;
                int h = (rowg >> 6) & 7, d0 = rowg & 63;
                float4 v = make_float4(acc[mi][ni][0] * sc, acc[mi][ni][1] * sc,
                                       acc[mi][ni][2] * sc, acc[mi][ni][3] * sc);
                float* dp = isk ? (float*)dst0 : (float*)dst1;
                size_t base = ((size_t)(bb * HEADS + h) * LKE + l) * 64 + d0;
                *(float4*)&dp[base] = v;
                if (isk) {
                    uint2 pk;
                    pk.x = f2q16(v.x) | (f2q16(v.y) << 16);
                    pk.y = f2q16(v.z) | (f2q16(v.w) << 16);
                    *(uint2*)&((unsigned*)dst2)[(((size_t)(bb * HEADS + h) * LKE + l) * 64 + d0) / 2] = pk;
                }
            } else {
                int h = rowg >> 6, d0 = rowg & 63;
                ushort4 u;
                u.x = f2bf(acc[mi][ni][0] * inv[ni]);
                u.y = f2bf(acc[mi][ni][1] * inv[ni]);
                u.z = f2bf(acc[mi][ni][2] * inv[ni]);
                u.w = f2bf(acc[mi][ni][3] * inv[ni]);
                unsigned short* qp = (unsigned short*)dst0;
                *(ushort4*)&qp[((size_t)(bb * HEADS + h) * LQ + l) * 64 + d0] = u;
            }
        }
    }
}

// -------- fused output: GEMM(w_out, afT) + per-location LN + residual --------
__global__ __launch_bounds__(256) void gemm_out_fused_kernel(
    const float* __restrict__ wmat,
    const unsigned short* __restrict__ afT,
    const float* __restrict__ g, const float* __restrict__ beta,
    const float* __restrict__ gamma, const float* __restrict__ qs_in,
    float* __restrict__ out) {
    int l0 = blockIdx.x * 64;
    int b  = blockIdx.y;
    int t = threadIdx.x, w = t >> 6, lane = t & 63;
    int lanelo = lane & 15, lanehi = lane >> 4;

    __shared__ __align__(16) char Wh[32768];
    __shared__ __align__(16) char Xh[8192];
    __shared__ float sLds[4][64];
    __shared__ float sqLds[4][64];
    __shared__ float gs[256], bs[256];

    gs[t] = g[t];
    bs[t] = beta[t];

    const unsigned short* xs = afT + ((size_t)b * LQ + l0) * 512;

    f32x4 acc[4][4];
#pragma unroll
    for (int mi = 0; mi < 4; mi++)
#pragma unroll
        for (int ni = 0; ni < 4; ni++) acc[mi][ni] = (f32x4){0.f, 0.f, 0.f, 0.f};

    int row0s = t >> 3, c80 = t & 7;
    int row1s = 32 + (t >> 3);
    int offs0 = (row0s * 128 + c80 * 16) ^ ((row0s & 7) << 4);
    int offs1 = (row1s * 128 + c80 * 16) ^ ((row1s & 7) << 4);

    for (int k0 = 0; k0 < 512; k0 += 64) {
        if (k0) __syncthreads();
#pragma unroll
        for (int gg = 0; gg < 8; gg++) {
            int row = gg * 32 + (t >> 3);
            int kc = (t & 7) * 8;
            const float* wp = wmat + (size_t)row * 512 + k0 + kc;
            bf16x8 hi;
#pragma unroll
            for (int i = 0; i < 8; i++) hi[i] = (short)f2bf(wp[i]);
            int off = (row * 128 + kc * 2) ^ ((row & 7) << 4);
            *(bf16x8*)(Wh + off) = hi;
        }
        *(bf16x8*)(Xh + offs0) = *(const bf16x8*)(xs + (size_t)row0s * 512 + k0 + c80 * 8);
        *(bf16x8*)(Xh + offs1) = *(const bf16x8*)(xs + (size_t)row1s * 512 + k0 + c80 * 8);
        __syncthreads();
#pragma unroll
        for (int kk = 0; kk < 2; kk++) {
            bf16x8 ah[4], bh_[4];
#pragma unroll
            for (int mi = 0; mi < 4; mi++) {
                int row = w * 64 + mi * 16 + lanelo;
                int off = (row * 128 + kk * 64 + lanehi * 16) ^ ((row & 7) << 4);
                ah[mi] = *(const bf16x8*)(Wh + off);
            }
#pragma unroll
            for (int ni = 0; ni < 4; ni++) {
                int row = ni * 16 + lanelo;
                int off = (row * 128 + kk * 64 + lanehi * 16) ^ ((row & 7) << 4);
                bh_[ni] = *(const bf16x8*)(Xh + off);
            }
#pragma unroll
            for (int mi = 0; mi < 4; mi++)
#pragma unroll
                for (int ni = 0; ni < 4; ni++)
                    acc[mi][ni] = mfma16(ah[mi], bh_[ni], acc[mi][ni]);
        }
    }

#pragma unroll
    for (int ni = 0; ni < 4; ni++) {
        float s = 0.f, sq = 0.f;
#pragma unroll
        for (int mi = 0; mi < 4; mi++)
#pragma unroll
            for (int rg = 0; rg < 4; rg++) {
                float v = acc[mi][ni][rg];
                s += v; sq += v * v;
            }
        s += __shfl_xor(s, 16);  s += __shfl_xor(s, 32);
        sq += __shfl_xor(sq, 16); sq += __shfl_xor(sq, 32);
        if (lanehi == 0) {
            sLds[w][ni * 16 + lanelo] = s;
            sqLds[w][ni * 16 + lanelo] = sq;
        }
    }
    __syncthreads();
    float mu_[4], rs_[4];
#pragma unroll
    for (int ni = 0; ni < 4; ni++) {
        int l = ni * 16 + lanelo;
        float s  = (sLds[0][l] + sLds[1][l]) + (sLds[2][l] + sLds[3][l]);
        float sq = (sqLds[0][l] + sqLds[1][l]) + (sqLds[2][l] + sqLds[3][l]);
        float m = s * (1.0f / 256.0f);
        float var = fmaxf(sq * (1.0f / 256.0f) - m * m, 0.f);
        mu_[ni] = m;
        rs_[ni] = rsqrtf(var + 1e-5f);
    }
    float gm = gamma[0];
#pragma unroll
    for (int mi = 0; mi < 4; mi++) {
#pragma unroll
        for (int ni = 0; ni < 4; ni++) {
            int l = ni * 16 + lanelo;
#pragma unroll
            for (int rg = 0; rg < 4; rg++) {
                int ch = w * 64 + mi * 16 + lanehi * 4 + rg;
                float xn = (acc[mi][ni][rg] - mu_[ni]) * rs_[ni] * gs[ch] + bs[ch];
                size_t oi = ((size_t)(b * DIMC + ch)) * LQ + l0 + l;
                out[oi] = gm * xn + qs_in[oi];
            }
        }
    }
}

// ------- exact f32 sampled-query recompute: LN -> w_q proj -> l2norm -> u16 ----
__global__ __launch_bounds__(256) void qsample_kernel(
    const float* __restrict__ x, const float* __restrict__ mu, const float* __restrict__ rs,
    const float* __restrict__ g, const float* __restrict__ beta,
    const float* __restrict__ w, const int* __restrict__ ridx,
    unsigned* __restrict__ Qint) {
    int lt = blockIdx.x, bh = blockIdx.y;
    int b = bh >> 3, h = bh & 7;
    int t = threadIdx.x, tx = t & 15, ty = t >> 4;
    __shared__ float Ws[64][33];
    __shared__ float Xs[32][65];
    __shared__ float Cs[64][65];
    __shared__ float nf[64];
    __shared__ int lidx[64];
    if (t < 64) lidx[t] = ridx[bh * TOPK + lt * 64 + t];
    __syncthreads();
    float acc[4][4];
#pragma unroll
    for (int a = 0; a < 4; a++)
#pragma unroll
        for (int c2 = 0; c2 < 4; c2++) acc[a][c2] = 0.f;
    for (int kc = 0; kc < DIMC; kc += 32) {
#pragma unroll
        for (int r = 0; r < 8; r++) {
            int f = r * 256 + t;
            int oi = f >> 5, kj = f & 31;
            Ws[oi][kj] = w[(size_t)(h * 64 + oi) * DIMC + kc + kj];
        }
#pragma unroll
        for (int r = 0; r < 8; r++) {
            int f = r * 256 + t;
            int kj = f >> 6, lj = f & 63;
            int l = lidx[lj];
            int loc = b * LQ + l;
            float v = x[(size_t)b * DIMC * LQ + (size_t)(kc + kj) * LQ + l];
            Xs[kj][lj] = (v - mu[loc]) * rs[loc] * g[kc + kj] + beta[kc + kj];
        }
        __syncthreads();
#pragma unroll
        for (int kj = 0; kj < 32; kj++) {
            float wr[4], xr[4];
#pragma unroll
            for (int a = 0; a < 4; a++) wr[a] = Ws[ty * 4 + a][kj];
#pragma unroll
            for (int c2 = 0; c2 < 4; c2++) xr[c2] = Xs[kj][tx * 4 + c2];
#pragma unroll
            for (int a = 0; a < 4; a++)
#pragma unroll
                for (int c2 = 0; c2 < 4; c2++) acc[a][c2] += wr[a] * xr[c2];
        }
        __syncthreads();
    }
#pragma unroll
    for (int a = 0; a < 4; a++)
#pragma unroll
        for (int c2 = 0; c2 < 4; c2++) Cs[ty * 4 + a][tx * 4 + c2] = acc[a][c2];
    __syncthreads();
    if (t < 64) {
        float sq = 0.f;
        for (int o = 0; o < 64; o++) { float v = Cs[o][t]; sq += v * v; }
        nf[t] = 1.0f / fmaxf(sqrtf(sq), 1e-12f);
    }
    __syncthreads();
#pragma unroll
    for (int r = 0; r < 8; r++) {
        int f = r * 256 + t;
        int dp = f & 31, lj = f >> 5;
        float v0 = Cs[dp * 2][lj] * nf[lj];
        float v1 = Cs[dp * 2 + 1][lj] * nf[lj];
        Qint[((size_t)bh * TOPK + (size_t)lt * 64 + lj) * 32 + dp] =
            f2q16(v0) | (f2q16(v1) << 16);
    }
}

// -------- L1 cdist + min via packed v_sad_u16; K in VGPRs, Q double-buffered ---
__global__ __launch_bounds__(256) __attribute__((amdgpu_waves_per_eu(4, 4)))
void cdist_sad_kernel(
    const unsigned* __restrict__ kint,
    const unsigned* __restrict__ Qint,
    unsigned* __restrict__ min_d4) {
    int bh = blockIdx.y;
    int key = blockIdx.x * 256 + threadIdx.x;
    int qz = blockIdx.z;
    const unsigned* kp = kint + ((size_t)bh * LKE + key) * 32;
    unsigned k[32];
#pragma unroll
    for (int d8 = 0; d8 < 8; d8++) {
        uint4 v = *(const uint4*)(kp + d8 * 4);
        k[d8 * 4 + 0] = v.x; k[d8 * 4 + 1] = v.y;
        k[d8 * 4 + 2] = v.z; k[d8 * 4 + 3] = v.w;
    }
#pragma unroll
    for (int d = 0; d < 32; d++) asm volatile("" : "+v"(k[d]));

    unsigned long long qaddr = (unsigned long long)(const void*)
        (Qint + ((size_t)bh * TOPK + (size_t)qz * (TOPK / 4)) * 32);
    u32x16 qa0, qa1, qb0, qb1;
    asm volatile(
        "s_load_dwordx16 %0, %2, 0x00\n\t"
        "s_load_dwordx16 %1, %2, 0x40"
        : "=s"(qa0), "=s"(qa1) : "s"(qaddr));
    unsigned best = 0xFFFFFFFFu;

#define S1(ACC, KK, QQ) asm("v_sad_u16 %0, %1, %2, %0" : "+v"(ACC) : "v"(KK), "s"(QQ));
#define S16(QV, KB) \
    S1(a0, k[KB + 0], QV[0])  S1(a1, k[KB + 1], QV[1]) \
    S1(a2, k[KB + 2], QV[2])  S1(a3, k[KB + 3], QV[3]) \
    S1(a0, k[KB + 4], QV[4])  S1(a1, k[KB + 5], QV[5]) \
    S1(a2, k[KB + 6], QV[6])  S1(a3, k[KB + 7], QV[7]) \
    S1(a0, k[KB + 8], QV[8])  S1(a1, k[KB + 9], QV[9]) \
    S1(a2, k[KB + 10], QV[10]) S1(a3, k[KB + 11], QV[11]) \
    S1(a0, k[KB + 12], QV[12]) S1(a1, k[KB + 13], QV[13]) \
    S1(a2, k[KB + 14], QV[14]) S1(a3, k[KB + 15], QV[15])

    for (int qi = 0; qi < TOPK / 4; qi += 2) {
        asm volatile(
            "s_load_dwordx16 %0, %2, 0x80\n\t"
            "s_load_dwordx16 %1, %2, 0xc0"
            : "=s"(qb0), "=s"(qb1) : "s"(qaddr));
        asm volatile("s_waitcnt lgkmcnt(2)" : "+s"(qa0), "+s"(qa1));
        {
            unsigned a0 = 0, a1 = 0, a2 = 0, a3 = 0;
            S16(qa0, 0) S16(qa1, 16)
            best = min(best, (a0 + a1) + (a2 + a3));
        }
        qaddr += 256;
        asm volatile(
            "s_load_dwordx16 %0, %2, 0x00\n\t"
            "s_load_dwordx16 %1, %2, 0x40"
            : "=s"(qa0), "=s"(qa1) : "s"(qaddr));
        asm volatile("s_waitcnt lgkmcnt(2)" : "+s"(qb0), "+s"(qb1));
        {
            unsigned a0 = 0, a1 = 0, a2 = 0, a3 = 0;
            S16(qb0, 0) S16(qb1, 16)
            best = min(best, (a0 + a1) + (a2 + a3));
        }
    }
#undef S16
#undef S1
    min_d4[((size_t)qz * NBH + bh) * LKE + key] = best;
}

// ------- radix-select 512 smallest per row; parallel bucket scan --------------
__global__ void select_topk_kernel(const unsigned* __restrict__ min_d4, int* __restrict__ isel) {
    int bh = blockIdx.x;
    int t = threadIdx.x;  // 256
    __shared__ unsigned su[LKE];
    __shared__ int hist[256];
    __shared__ int scan[256];
    __shared__ int sb[2];
    for (int i = t; i < LKE; i += 256) {
        unsigned a = min(min_d4[(size_t)bh * LKE + i],
                         min_d4[(size_t)(NBH + bh) * LKE + i]);
        unsigned b = min(min_d4[(size_t)(2 * NBH + bh) * LKE + i],
                         min_d4[(size_t)(3 * NBH + bh) * LKE + i]);
        su[i] = min(a, b);
    }
    unsigned prefix = 0, mask = 0;
    int need = TOPK;
    for (int shift = 24; shift >= 0; shift -= 8) {
        hist[t] = 0;
        __syncthreads();
        for (int i = t; i < LKE; i += 256) {
            unsigned u = su[i];
            if ((u & mask) == prefix) atomicAdd(&hist[(u >> shift) & 255], 1);
        }
        __syncthreads();
        scan[t] = hist[t];
        __syncthreads();
#pragma unroll
        for (int d = 1; d < 256; d <<= 1) {
            int v = (t >= d) ? scan[t - d] : 0;
            __syncthreads();
            scan[t] += v;
            __syncthreads();
        }
        int excl = (t == 0) ? 0 : scan[t - 1];
        if (scan[t] >= need && excl < need) {
            sb[0] = t;
            sb[1] = need - excl;
        }
        __syncthreads();
        prefix |= ((unsigned)sb[0]) << shift;
        mask |= (255u << shift);
        need = sb[1];
        __syncthreads();
    }
    if (t < 64) {
        int pos = 0, eqseen = 0;
        unsigned long long lanem1 = (t == 0) ? 0ull : ((1ull << t) - 1ull);
        for (int i0 = 0; i0 < LKE; i0 += 64) {
            unsigned u = su[i0 + t];
            bool lt = (u < prefix);
            bool eq = (u == prefix);
            unsigned long long be = __ballot(eq);
            int eqbefore = __popcll(be & lanem1);
            bool take = lt || (eq && (eqseen + eqbefore) < need);
            unsigned long long bt = __ballot(take);
            if (take) isel[bh * TOPK + pos + __popcll(bt & lanem1)] = i0 + t;
            pos += __popcll(bt);
            eqseen += __popcll(be);
        }
    }
}

// -------- gather selected K (straight) + V (transposed), one launch -----------
__global__ __launch_bounds__(256) void gather_kv_kernel(
    const float* __restrict__ kf, const float* __restrict__ vf,
    const int* __restrict__ isel,
    unsigned short* __restrict__ kselh, unsigned short* __restrict__ vTh) {
    int bh = blockIdx.y, kc = blockIdx.x * 64;
    int t = threadIdx.x;
    __shared__ float T[64][65];
    __shared__ int rows[64];
    if (t < 64) rows[t] = isel[bh * TOPK + kc + t];
    __syncthreads();
#pragma unroll
    for (int r = 0; r < 16; r++) {
        int f = r * 256 + t;
        int key = f >> 6, d = f & 63;
        kselh[((size_t)bh * TOPK + kc + key) * 64 + d] =
            f2bf(kf[((size_t)bh * LKE + rows[key]) * 64 + d]);
    }
#pragma unroll
    for (int r = 0; r < 4; r++) {
        int c = r * 256 + t;
        int row = c >> 4, c4 = c & 15;
        float4 v = *(const float4*)(vf + ((size_t)bh * LKE + rows[row]) * 64 + c4 * 4);
        T[row][c4 * 4 + 0] = v.x; T[row][c4 * 4 + 1] = v.y;
        T[row][c4 * 4 + 2] = v.z; T[row][c4 * 4 + 3] = v.w;
    }
    __syncthreads();
#pragma unroll
    for (int r = 0; r < 16; r++) {
        int f = r * 256 + t;
        int d = f >> 6, key = f & 63;
        vTh[(size_t)bh * 64 * TOPK + (size_t)d * TOPK + kc + key] = f2bf(T[key][d]);
    }
}

// ---------------- MFMA flash attention, 128 q-rows/block (R15 verified) -------
__global__ __launch_bounds__(256) void attn_mfma_kernel(
    const unsigned short* __restrict__ qh,
    const unsigned short* __restrict__ kselh,
    const unsigned short* __restrict__ vTh,
    unsigned short* __restrict__ afT) {
    int bh = blockIdx.y, rt = blockIdx.x;
    int bq = bh >> 3, h = bh & 7;
    int t = threadIdx.x, w = t >> 6, lane = t & 63;
    __shared__ unsigned short Ks[2][64 * 64];
    __shared__ unsigned short Vts[2][64 * 64];
    __shared__ unsigned short Ps[4][2][16 * 64];

    const unsigned short* qb = qh + ((size_t)bh * LQ + (size_t)rt * 128) * 64;
    const unsigned short* kb = kselh + (size_t)bh * TOPK * 64;
    const unsigned short* vb = vTh + (size_t)bh * 64 * TOPK;

    int lanelo = lane & 15, lanehi = lane >> 4;

    int row0s = t >> 3, c80 = t & 7;
    int row1s = 32 + (t >> 3), c81 = t & 7;
    int offs0 = (row0s * 128 + c80 * 16) ^ ((row0s & 7) << 4);
    int offs1 = (row1s * 128 + c81 * 16) ^ ((row1s & 7) << 4);

    bf16x8 qfrag[2][2];
#pragma unroll
    for (int s = 0; s < 2; s++)
#pragma unroll
        for (int kk = 0; kk < 2; kk++) {
            int row = s * 64 + w * 16 + lanelo;
            qfrag[s][kk] = *(const bf16x8*)(qb + (size_t)row * 64 + kk * 32 + lanehi * 8);
        }

    {
        *(bf16x8*)((char*)Ks[0] + offs0) = *(const bf16x8*)(kb + row0s * 64 + c80 * 8);
        *(bf16x8*)((char*)Ks[0] + offs1) = *(const bf16x8*)(kb + row1s * 64 + c81 * 8);
        *(bf16x8*)((char*)Vts[0] + offs0) = *(const bf16x8*)(vb + row0s * TOPK + c80 * 8);
        *(bf16x8*)((char*)Vts[0] + offs1) = *(const bf16x8*)(vb + row1s * TOPK + c81 * 8);
    }
    __syncthreads();

    f32x4 o[2][4];
#pragma unroll
    for (int s = 0; s < 2; s++)
#pragma unroll
        for (int m = 0; m < 4; m++) o[s][m] = (f32x4){0.f, 0.f, 0.f, 0.f};
    float part[2][4] = {{0.f, 0.f, 0.f, 0.f}, {0.f, 0.f, 0.f, 0.f}};
    int cur = 0;

    for (int ch = 0; ch < 8; ch++) {
        bf16x8 knx0, knx1, vnx0, vnx1;
        if (ch < 7) {
            int kc0 = (ch + 1) * 64;
            knx0 = *(const bf16x8*)(kb + (kc0 + row0s) * 64 + c80 * 8);
            knx1 = *(const bf16x8*)(kb + (kc0 + row1s) * 64 + c81 * 8);
            vnx0 = *(const bf16x8*)(vb + row0s * TOPK + kc0 + c80 * 8);
            vnx1 = *(const bf16x8*)(vb + row1s * TOPK + kc0 + c81 * 8);
        }
        bf16x8 kfr[4][2];
#pragma unroll
        for (int n = 0; n < 4; n++)
#pragma unroll
            for (int kk = 0; kk < 2; kk++) {
                int row = n * 16 + lanelo;
                kfr[n][kk] = *(const bf16x8*)((char*)Ks[cur] +
                    ((row * 128 + kk * 64 + lanehi * 16) ^ ((row & 7) << 4)));
            }
#pragma unroll
        for (int s = 0; s < 2; s++) {
            f32x4 sv[4];
#pragma unroll
            for (int n = 0; n < 4; n++) {
                sv[n] = (f32x4){0.f, 0.f, 0.f, 0.f};
#pragma unroll
                for (int kk = 0; kk < 2; kk++)
                    sv[n] = mfma16(qfrag[s][kk], kfr[n][kk], sv[n]);
            }
            unsigned short* pw = Ps[w][s];
#pragma unroll
            for (int n = 0; n < 4; n++) {
#pragma unroll
                for (int rg = 0; rg < 4; rg++) {
                    float p = __expf(sv[n][rg]);
                    unsigned short ph = (unsigned short)(__float_as_uint(p) >> 16);
                    part[s][rg] += bf2f(ph);
                    int row = lanehi * 4 + rg, col = n * 16 + lanelo;
                    *(unsigned short*)((char*)pw +
                        ((row * 128 + col * 2) ^ ((row & 7) << 4))) = ph;
                }
            }
        }
        bf16x8 vfr[4][2];
#pragma unroll
        for (int m = 0; m < 4; m++)
#pragma unroll
            for (int kk = 0; kk < 2; kk++) {
                int row = m * 16 + lanelo;
                vfr[m][kk] = *(const bf16x8*)((char*)Vts[cur] +
                    ((row * 128 + kk * 64 + lanehi * 16) ^ ((row & 7) << 4)));
            }
#pragma unroll
        for (int s = 0; s < 2; s++) {
            bf16x8 pfrag[2];
#pragma unroll
            for (int kk = 0; kk < 2; kk++) {
                int row = lanelo;
                pfrag[kk] = *(const bf16x8*)((char*)Ps[w][s] +
                    ((row * 128 + kk * 64 + lanehi * 16) ^ ((row & 7) << 4)));
            }
#pragma unroll
            for (int m = 0; m < 4; m++)
#pragma unroll
                for (int kk = 0; kk < 2; kk++)
                    o[s][m] = mfma16(pfrag[kk], vfr[m][kk], o[s][m]);
        }
        if (ch < 7) {
            *(bf16x8*)((char*)Ks[cur ^ 1] + offs0) = knx0;
            *(bf16x8*)((char*)Ks[cur ^ 1] + offs1) = knx1;
            *(bf16x8*)((char*)Vts[cur ^ 1] + offs0) = vnx0;
            *(bf16x8*)((char*)Vts[cur ^ 1] + offs1) = vnx1;
        }
        __syncthreads();
        cur ^= 1;
    }
#pragma unroll
    for (int s = 0; s < 2; s++) {
#pragma unroll
        for (int rg = 0; rg < 4; rg++) {
            float v = part[s][rg];
            v += __shfl_xor(v, 1); v += __shfl_xor(v, 2);
            v += __shfl_xor(v, 4); v += __shfl_xor(v, 8);
            float invs = 1.0f / v;
            int l = rt * 128 + s * 64 + w * 16 + lanehi * 4 + rg;
            size_t base = ((size_t)bq * LQ + l) * 512 + h * 64 + lanelo;
#pragma unroll
            for (int m = 0; m < 4; m++)
                afT[base + m * 16] = f2bf(o[s][m][rg] * invs);
        }
    }
}

extern "C" void kernel_launch(void* const* d_in, const int* in_sizes, int n_in,
                              void* d_out, int out_size, void* d_ws, size_t ws_size,
                              hipStream_t stream) {
    const float* qs_in = (const float*)d_in[0];
    const float* ctx   = (const float*)d_in[1];
    const int*   ridx  = (const int*)d_in[2];
    const float* g_ctx = (const float*)d_in[3];
    const float* b_ctx = (const float*)d_in[4];
    const float* g_qs  = (const float*)d_in[5];
    const float* b_qs  = (const float*)d_in[6];
    const float* w_kv  = (const float*)d_in[7];
    const float* w_q   = (const float*)d_in[8];
    const float* w_out = (const float*)d_in[9];
    const float* g_out = (const float*)d_in[10];
    const float* b_out = (const float*)d_in[11];
    const float* gamma = (const float*)d_in[12];
    float* out = (float*)d_out;

    char* ws = (char*)d_ws;
    size_t off = 0;
    auto alloc = [&](size_t bytes) { char* p = ws + off; off += (bytes + 255) & ~(size_t)255; return p; };

    float*          kf    = (float*)alloc((size_t)NBH * LKE * 64 * 4);
    float*          vf    = (float*)alloc((size_t)NBH * LKE * 64 * 4);
    unsigned*       kint  = (unsigned*)alloc((size_t)NBH * LKE * 32 * 4);
    unsigned short* qh    = (unsigned short*)alloc((size_t)NBH * LQ * 64 * 2);
    char*           uni   = alloc((size_t)NB * LQ * INNER * 2);
    unsigned short* ctxT_hi = (unsigned short*)(uni);
    unsigned short* ctxT_lo = (unsigned short*)(uni + (size_t)NB * LKE * DIMC * 2);
    unsigned short* qsT_hi  = (unsigned short*)(uni + (size_t)2 * NB * LKE * DIMC * 2);
    unsigned short* afT     = (unsigned short*)(uni);

    unsigned*       Qint  = (unsigned*)alloc((size_t)NBH * TOPK * 32 * 4);
    unsigned short* kselh = (unsigned short*)alloc((size_t)NBH * TOPK * 64 * 2);
    unsigned short* vTh   = (unsigned short*)alloc((size_t)NBH * 64 * TOPK * 2);
    unsigned*       min_d4= (unsigned*)alloc((size_t)4 * NBH * LKE * 4);
    float*          mu_c  = (float*)alloc(NB * LKE * 4);
    float*          rs_c  = (float*)alloc(NB * LKE * 4);
    float*          mu_q  = (float*)alloc(NB * LQ * 4);
    float*          rs_q  = (float*)alloc(NB * LQ * 4);
    int*            isel  = (int*)alloc(NBH * TOPK * 4);

    stats_all_kernel<<<(NB * (LKE + LQ)) / 256, 256, 0, stream>>>(
        ctx, qs_in, mu_c, rs_c, mu_q, rs_q);
    ln_transpose_kernel<true><<<dim3(LKE / 64, DIMC / 64, NB), 256, 0, stream>>>(
        ctx, mu_c, rs_c, g_ctx, b_ctx, LKE, ctxT_hi, ctxT_lo);
    ln_transpose_kernel<false><<<dim3(LQ / 64, DIMC / 64, NB), 256, 0, stream>>>(
        qs_in, mu_q, rs_q, g_qs, b_qs, LQ, qsT_hi, nullptr);
    gemm_mfma_kernel<0><<<dim3(LKE / 128, 8, NB), 256, 0, stream>>>(
        w_kv, ctxT_hi, ctxT_lo, kf, vf, kint);
    gemm_mfma_kernel<1><<<dim3(LQ / 128, 4, NB), 256, 0, stream>>>(
        w_q, qsT_hi, qsT_hi, qh, nullptr, nullptr);
    qsample_kernel<<<dim3(TOPK / 64, NBH), 256, 0, stream>>>(
        qs_in, mu_q, rs_q, g_qs, b_qs, w_q, ridx, Qint);
    cdist_sad_kernel<<<dim3(LKE / 256, NBH, 4), 256, 0, stream>>>(kint, Qint, min_d4);
    select_topk_kernel<<<NBH, 256, 0, stream>>>(min_d4, isel);
    gather_kv_kernel<<<dim3(TOPK / 64, NBH), 256, 0, stream>>>(kf, vf, isel, kselh, vTh);
    attn_mfma_kernel<<<dim3(LQ / 128, NBH), 256, 0, stream>>>(qh, kselh, vTh, afT);
    gemm_out_fused_kernel<<<dim3(LQ / 64, NB), 256, 0, stream>>>(
        w_out, afT, g_out, b_out, gamma, qs_in, out);
}